// Round 7
// baseline (478.146 us; speedup 1.0000x reference)
//
#include <hip/hip_runtime.h>
#include <hip/hip_bf16.h>

#define NN   10000
#define SS   4
#define BB   40000
#define LLEN 8
#define DD   193
#define G3   192

typedef __attribute__((ext_vector_type(8))) short bf16x8;
typedef __attribute__((ext_vector_type(4))) short short4v;
typedef __attribute__((ext_vector_type(4))) float f32x4;

// ws layout (bytes)
#define OFF_DMAX 0
#define OFF_DEGN 1024
#define OFF_FRAG 65536                 // 156 frags x 1KB = 156 KB (ends 221 KB)
#define OFF_A    262144                // 10000*192*4 = 7.68 MB (ends 7.94 MB)
#define OFF_YF   (8ull*1024*1024)      // 40.96 MB
#define OFF_YB   (49ull*1024*1024)     // 40.96 MB
#define OFF_HFB  (90ull*1024*1024)     // 10.24 MB (ends 100.24 MB, same as R5)

// fragment blob indexing (each frag = 64 lanes x 8 bf16 = 1 KB)
#define FB_FRAG(dir,T,ch)  (((dir)*12 + (T))*3 + (ch))   // 72 frags: Whh(2ch) + A2(1ch)
#define FIN_FRAG(T,ch)     (72 + (T)*7 + (ch))           // 84 frags: U(2) + Wy(4) + A5(1)

__device__ __forceinline__ float sigm(float x){ return 1.0f/(1.0f+__expf(-x)); }
__device__ __forceinline__ float tanh_(float x){
  float e = __expf(-2.0f*fabsf(x));
  float t = (1.0f-e)/(1.0f+e);
  return x>=0.0f ? t : -t;
}
__device__ __forceinline__ short f2b(float f){            // RNE float->bf16
  unsigned u = __builtin_bit_cast(unsigned, f);
  u = u + 0x7FFFu + ((u>>16)&1u);
  return (short)(u>>16);
}
__device__ __forceinline__ float b2f(short s){
  unsigned u = ((unsigned)(unsigned short)s)<<16;
  return __builtin_bit_cast(float, u);
}

__global__ void k_zero(int* dmax){
  if (threadIdx.x==0 && blockIdx.x==0) *dmax = 0;
}

__global__ void k_degmax(const int* __restrict__ walks, const int* __restrict__ indeg,
                         int* __restrict__ dmax){
  int i = blockIdx.x*blockDim.x + threadIdx.x;
  int d = 0;
  if (i < SS*NN*LLEN) d = indeg[walks[i]];
  #pragma unroll
  for (int off=32; off>0; off>>=1) d = max(d, __shfl_xor(d, off));
  if ((threadIdx.x&63)==0 && d>0) atomicMax(dmax, d);
}

__global__ void k_degn(const int* __restrict__ indeg, const int* __restrict__ dmax,
                       float* __restrict__ degn){
  int n = blockIdx.x*blockDim.x + threadIdx.x;
  if (n < NN) degn[n] = (float)indeg[n] / (float)(*dmax);
}

// Pre-pack MFMA A-operand (weight) fragments into a fragment-ordered bf16 blob.
// One block builds one 1KB fragment; lane (c=lane&15, a=lane>>4) holds
// row g=16T+c, k-slice a*8..a*8+7 — exactly the 16x16x32 A-frag layout.
__global__ __launch_bounds__(64) void k_prep(
    const float* __restrict__ Wih_f, const float* __restrict__ Whh_f,
    const float* __restrict__ bih_f, const float* __restrict__ bhh_f,
    const float* __restrict__ Wih_b, const float* __restrict__ Whh_b,
    const float* __restrict__ bih_b, const float* __restrict__ bhh_b,
    const float* __restrict__ W, const float* __restrict__ U,
    const float* __restrict__ bhh,
    short* __restrict__ blob)
{
  int f = blockIdx.x;
  int lane = threadIdx.x;
  int c = lane & 15, a = lane >> 4;
  float v[8];
  if (f < 72){
    int dir = f / 36, rem = f % 36, T = rem / 3, ch = rem % 3;
    int g = 16*T + c;
    const float* Whh = dir ? Whh_b : Whh_f;
    const float* Wih = dir ? Wih_b : Wih_f;
    const float* bih = dir ? bih_b : bih_f;
    const float* bhd = dir ? bhh_b : bhh_f;
    if (ch < 2){
      #pragma unroll
      for (int j=0;j<8;++j) v[j] = Whh[g*64 + ch*32 + a*8 + j];
    } else {
      #pragma unroll
      for (int j=0;j<8;++j){
        int k = a*8 + j;
        v[j] = (k==0) ? Wih[2*g] : (k==1) ? Wih[2*g+1]
             : (k==2) ? (bih[g] + (g<128 ? bhd[g] : 0.0f)) : 0.0f;
      }
    }
  } else {
    int f2 = f - 72, T = f2 / 7, ch = f2 % 7;
    int g = 16*T + c;
    if (ch < 2){
      #pragma unroll
      for (int j=0;j<8;++j) v[j] = U[g*64 + ch*32 + a*8 + j];
    } else if (ch < 6){
      #pragma unroll
      for (int j=0;j<8;++j) v[j] = W[(long)g*DD + 64 + (ch-2)*32 + a*8 + j];
    } else {
      #pragma unroll
      for (int j=0;j<8;++j){
        int k = a*8 + j;
        v[j] = (k==0) ? W[(long)g*DD + 192] : (k==1) ? (g<128 ? bhh[g] : 0.0f) : 0.0f;
      }
    }
  }
  #pragma unroll
  for (int j=0;j<8;++j) blob[(long)f*512 + lane*8 + j] = f2b(v[j]);
}

// A[n][g] = bih[g] + sum_k h[n][k]*Wih[g][k]  (cols 0..63)
__global__ __launch_bounds__(192) void k_A(const float* __restrict__ h,
                                           const float* __restrict__ Wih,
                                           const float* __restrict__ bih,
                                           float* __restrict__ A){
  int g = threadIdx.x;
  float w[64];
  #pragma unroll
  for (int k=0;k<64;++k) w[k] = Wih[g*DD + k];
  float bg = bih[g];
  __shared__ float hs[64];
  int n0 = blockIdx.x*32;
  for (int j=0;j<32;++j){
    int n = n0 + j;
    if (n >= NN) break;
    __syncthreads();
    if (g < 64) hs[g] = h[n*64+g];
    __syncthreads();
    float acc = bg;
    #pragma unroll
    for (int k=0;k<64;++k) acc += w[k]*hs[k];
    A[n*G3 + g] = acc;
  }
}

// ---------------- fwd/bwd GRU: 2 waves x 32 seqs (SB=2), weights from global blob ----
// Per q in 0..3: tiles (q, 4+q, 8+q) = (r,z,n) for channels 16q..16q+15; only
// 8 f32x4 accumulators live. Weight frag loaded once, used for both seq-groups.
__global__ __launch_bounds__(128, 2) void k_fb(
    const int* __restrict__ walks, const short* __restrict__ blob,
    const float* __restrict__ bhh_f, const float* __restrict__ bhh_b,
    short* __restrict__ yf_out, short* __restrict__ yb_out,
    short* __restrict__ hfb)
{
  const int dir = blockIdx.y;
  const float* bhh = dir ? bhh_b : bhh_f;
  short* yout = dir ? yb_out : yf_out;

  __shared__ __align__(16) short hl[64*64];     // swizzled h bf16, wave-private rows
  __shared__ __align__(16) float sc[64*8*2];
  __shared__ __align__(16) float bhn[64];

  const int tid = threadIdx.x;
  const int b0  = blockIdx.x*64;

  if (tid < 64) bhn[tid] = bhh[128+tid];
  for (int idx = tid; idx < 512; idx += 128){
    int s = idx>>3, t = idx&7, p = 7-t;
    const int* wr = walks + (long)(b0+s)*LLEN;
    int wp = wr[p]; int u = 7;
    #pragma unroll
    for (int j=7;j>=0;--j) if (wr[j]==wp) u = j;
    float si, ci;
    __sincosf((float)u * 0.7853981633974483f, &si, &ci);
    sc[idx*2] = si; sc[idx*2+1] = ci;
  }

  const int lane = tid & 63;
  const int wv   = tid >> 6;
  const int c    = lane & 15;
  const int a    = lane >> 4;
  const int s0   = wv*32 + c;
  const int s1   = wv*32 + 16 + c;

  float hreg[2][4][4];
  short4v z4 = {0,0,0,0};
  #pragma unroll
  for (int sb=0;sb<2;++sb){
    int s = sb ? s1 : s0;
    #pragma unroll
    for (int q=0;q<4;++q){
      #pragma unroll
      for (int r=0;r<4;++r) hreg[sb][q][r] = 0.0f;
      int i0 = q*16 + 4*a;
      *(short4v*)&hl[s*64 + (i0 ^ ((s&7)<<3))] = z4;
    }
  }
  __syncthreads();

  const bf16x8* FB = (const bf16x8*)blob;

  for (int ss=0; ss<8; ++ss){
    const int t = dir ? 7-ss : ss;
    asm volatile("s_waitcnt lgkmcnt(0)" ::: "memory");
    bf16x8 bh0[2], bh1[2], b2[2];
    #pragma unroll
    for (int sb=0;sb<2;++sb){
      int s = sb ? s1 : s0;
      bh0[sb] = *(const bf16x8*)&hl[s*64 + ((a*8)      ^ ((s&7)<<3))];
      bh1[sb] = *(const bf16x8*)&hl[s*64 + ((32 + a*8) ^ ((s&7)<<3))];
      float si = sc[(s*8+t)*2], ci = sc[(s*8+t)*2+1];
      bf16x8 bb = {0,0,0,0,0,0,0,0};
      if (a == 0){ bb[0] = f2b(si); bb[1] = f2b(ci); bb[2] = (short)0x3F80; }
      b2[sb] = bb;
    }

    #pragma unroll
    for (int q=0;q<4;++q){
      f32x4 ar[2], az[2], an1[2], an2[2];
      #pragma unroll
      for (int sb=0;sb<2;++sb){
        ar[sb].x=0;ar[sb].y=0;ar[sb].z=0;ar[sb].w=0;
        az[sb]=ar[sb]; an1[sb]=ar[sb]; an2[sb]=ar[sb];
      }
      #pragma unroll
      for (int ch=0;ch<3;++ch){
        bf16x8 fr = FB[(long)FB_FRAG(dir,   q,ch)*64 + lane];
        bf16x8 fz = FB[(long)FB_FRAG(dir, 4+q,ch)*64 + lane];
        bf16x8 fn = FB[(long)FB_FRAG(dir, 8+q,ch)*64 + lane];
        #pragma unroll
        for (int sb=0;sb<2;++sb){
          bf16x8 bb = (ch==0) ? bh0[sb] : (ch==1) ? bh1[sb] : b2[sb];
          ar[sb] = __builtin_amdgcn_mfma_f32_16x16x32_bf16(fr, bb, ar[sb], 0,0,0);
          az[sb] = __builtin_amdgcn_mfma_f32_16x16x32_bf16(fz, bb, az[sb], 0,0,0);
          if (ch < 2) an1[sb] = __builtin_amdgcn_mfma_f32_16x16x32_bf16(fn, bb, an1[sb], 0,0,0);
          else        an2[sb] = __builtin_amdgcn_mfma_f32_16x16x32_bf16(fn, bb, an2[sb], 0,0,0);
        }
      }
      f32x4 bv = *(const f32x4*)&bhn[q*16 + 4*a];
      #pragma unroll
      for (int sb=0;sb<2;++sb){
        int s = sb ? s1 : s0;
        int sg = b0 + s;
        short4v pack;
        #pragma unroll
        for (int r=0;r<4;++r){
          float rr = sigm(ar[sb][r]);
          float zz = sigm(az[sb][r]);
          float hn_ = an1[sb][r] + bv[r];
          float xn  = an2[sb][r];
          float nn = tanh_(xn + rr*hn_);
          float hv = (1.0f-zz)*nn + zz*hreg[sb][q][r];
          hreg[sb][q][r] = hv;
          pack[r] = f2b(hv);
        }
        int i0 = q*16 + 4*a;
        *(short4v*)&hl[s*64 + (i0 ^ ((s&7)<<3))] = pack;
        *(short4v*)(yout + ((long)(t*16 + 4*q + a)*BB + sg)*4) = pack;
      }
    }
  }

  #pragma unroll
  for (int sb=0;sb<2;++sb){
    int s = sb ? s1 : s0;
    int sg = b0 + s;
    #pragma unroll
    for (int q=0;q<4;++q){
      int i0 = q*16 + 4*a;
      short4v pk;
      #pragma unroll
      for (int r=0;r<4;++r) pk[r] = f2b(hreg[sb][q][r]);
      *(short4v*)(hfb + ((long)dir*BB + sg)*64 + i0) = pk;
    }
  }
}

// ---------------- final GRU: K = 64(U·h) + 128(Wy·y) + 32(deg/bias), blob weights ----
__global__ __launch_bounds__(128, 2) void k_final(
    const int* __restrict__ walks, const float* __restrict__ degn,
    const float* __restrict__ A, const short* __restrict__ blob,
    const float* __restrict__ bhh,
    const short* __restrict__ yf, const short* __restrict__ yb,
    const short* __restrict__ hfb,
    float* __restrict__ out)
{
  __shared__ __align__(16) short hl[64*64];
  __shared__ __align__(16) int   node[64*8];
  __shared__ __align__(16) float degl[64*8];
  __shared__ __align__(16) float bhn[64];

  const int tid = threadIdx.x;
  const int b0  = blockIdx.x*64;

  if (tid < 64) bhn[tid] = bhh[128+tid];
  for (int idx = tid; idx < 512; idx += 128){
    int s = idx>>3, t = idx&7;
    int nd = walks[(long)(b0+s)*LLEN + 7-t];
    node[idx] = nd;
    degl[idx] = degn[nd];
  }

  const int lane = tid & 63;
  const int wv   = tid >> 6;
  const int c    = lane & 15;
  const int a    = lane >> 4;
  const int s0   = wv*32 + c;
  const int s1   = wv*32 + 16 + c;

  float hreg[2][4][4];
  #pragma unroll
  for (int sb=0;sb<2;++sb){
    int s = sb ? s1 : s0;
    int sg = b0 + s;
    #pragma unroll
    for (int q=0;q<4;++q){
      int i0 = q*16 + 4*a;
      short4v hf4 = *(const short4v*)(hfb + (long)sg*64 + i0);
      short4v hb4 = *(const short4v*)(hfb + ((long)BB + sg)*64 + i0);
      short4v pk;
      #pragma unroll
      for (int r=0;r<4;++r){
        float hv = 0.5f*(b2f(hf4[r]) + b2f(hb4[r]));
        hreg[sb][q][r] = hv;
        pk[r] = f2b(hv);
      }
      *(short4v*)&hl[s*64 + (i0 ^ ((s&7)<<3))] = pk;
    }
  }
  __syncthreads();

  const bf16x8* FB = (const bf16x8*)blob;

  auto ldy = [&](const short* Y, int t, int kh, int sg, bf16x8& dst){
    int kb  = kh*8 + a*2;
    long base = ((long)(t*16 + kb)*BB + sg)*4;
    short4v lo = *(const short4v*)(Y + base);
    short4v hi = *(const short4v*)(Y + base + (long)BB*4);
    dst[0]=lo[0]; dst[1]=lo[1]; dst[2]=lo[2]; dst[3]=lo[3];
    dst[4]=hi[0]; dst[5]=hi[1]; dst[6]=hi[2]; dst[7]=hi[3];
  };

  for (int t=0; t<8; ++t){
    asm volatile("s_waitcnt lgkmcnt(0)" ::: "memory");
    bf16x8 bh0[2], bh1[2], b5[2], yfc[2][2], ybc[2][2];
    int nd_[2];
    #pragma unroll
    for (int sb=0;sb<2;++sb){
      int s = sb ? s1 : s0;
      int sg = b0 + s;
      bh0[sb] = *(const bf16x8*)&hl[s*64 + ((a*8)      ^ ((s&7)<<3))];
      bh1[sb] = *(const bf16x8*)&hl[s*64 + ((32 + a*8) ^ ((s&7)<<3))];
      bf16x8 bb = {0,0,0,0,0,0,0,0};
      if (a == 0){ bb[0] = f2b(degl[s*8+t]); bb[1] = (short)0x3F80; }
      b5[sb] = bb;
      ldy(yf, t, 0, sg, yfc[sb][0]); ldy(yf, t, 1, sg, yfc[sb][1]);
      ldy(yb, t, 0, sg, ybc[sb][0]); ldy(yb, t, 1, sg, ybc[sb][1]);
      nd_[sb] = node[s*8 + t];
    }

    #pragma unroll
    for (int q=0;q<4;++q){
      f32x4 ar[2], az[2], an1[2], an2[2];
      #pragma unroll
      for (int sb=0;sb<2;++sb){
        ar[sb].x=0;ar[sb].y=0;ar[sb].z=0;ar[sb].w=0;
        az[sb]=ar[sb]; an1[sb]=ar[sb]; an2[sb]=ar[sb];
      }
      #pragma unroll
      for (int ch=0;ch<7;++ch){
        bf16x8 fr = FB[(long)FIN_FRAG(   q,ch)*64 + lane];
        bf16x8 fz = FB[(long)FIN_FRAG( 4+q,ch)*64 + lane];
        bf16x8 fn = FB[(long)FIN_FRAG( 8+q,ch)*64 + lane];
        #pragma unroll
        for (int sb=0;sb<2;++sb){
          bf16x8 bb = (ch==0) ? bh0[sb] : (ch==1) ? bh1[sb]
                    : (ch==2) ? yfc[sb][0] : (ch==3) ? yfc[sb][1]
                    : (ch==4) ? ybc[sb][0] : (ch==5) ? ybc[sb][1] : b5[sb];
          ar[sb] = __builtin_amdgcn_mfma_f32_16x16x32_bf16(fr, bb, ar[sb], 0,0,0);
          az[sb] = __builtin_amdgcn_mfma_f32_16x16x32_bf16(fz, bb, az[sb], 0,0,0);
          if (ch < 2) an1[sb] = __builtin_amdgcn_mfma_f32_16x16x32_bf16(fn, bb, an1[sb], 0,0,0);
          else        an2[sb] = __builtin_amdgcn_mfma_f32_16x16x32_bf16(fn, bb, an2[sb], 0,0,0);
        }
      }
      f32x4 bv = *(const f32x4*)&bhn[q*16 + 4*a];
      #pragma unroll
      for (int sb=0;sb<2;++sb){
        int s = sb ? s1 : s0;
        const float* Ab = A + (long)nd_[sb]*G3 + q*16 + 4*a;
        f32x4 Agr = *(const f32x4*)(Ab);
        f32x4 Agz = *(const f32x4*)(Ab + 64);
        f32x4 Agn = *(const f32x4*)(Ab + 128);
        short4v pack;
        #pragma unroll
        for (int r=0;r<4;++r){
          float rr = sigm(ar[sb][r]  + Agr[r]);
          float zz = sigm(az[sb][r]  + Agz[r]);
          float hn_ = an1[sb][r] + bv[r];
          float xn  = an2[sb][r] + Agn[r];
          float nn = tanh_(xn + rr*hn_);
          float hv = (1.0f-zz)*nn + zz*hreg[sb][q][r];
          hreg[sb][q][r] = hv;
          pack[r] = f2b(hv);
        }
        int i0 = q*16 + 4*a;
        *(short4v*)&hl[s*64 + (i0 ^ ((s&7)<<3))] = pack;
      }
    }
  }

  #pragma unroll
  for (int sb=0;sb<2;++sb){
    int s = sb ? s1 : s0;
    int sg = b0 + s;
    #pragma unroll
    for (int q=0;q<4;++q){
      int i0 = q*16 + 4*a;
      f32x4 o;
      #pragma unroll
      for (int r=0;r<4;++r) o[r] = hreg[sb][q][r];
      *(f32x4*)(out + (long)sg*64 + i0) = o;
    }
  }
}

extern "C" void kernel_launch(void* const* d_in, const int* in_sizes, int n_in,
                              void* d_out, int out_size, void* d_ws, size_t ws_size,
                              hipStream_t stream) {
  const float* h     = (const float*)d_in[0];
  const int*   walks = (const int*)d_in[1];
  const int*   indeg = (const int*)d_in[2];
  const float* Wf    = (const float*)d_in[3];
  const float* Uf    = (const float*)d_in[4];
  const float* bif   = (const float*)d_in[5];
  const float* bhf   = (const float*)d_in[6];
  const float* Wb    = (const float*)d_in[7];
  const float* Ub    = (const float*)d_in[8];
  const float* bib   = (const float*)d_in[9];
  const float* bhb   = (const float*)d_in[10];
  const float* W     = (const float*)d_in[11];
  const float* U     = (const float*)d_in[12];
  const float* bi    = (const float*)d_in[13];
  const float* bh    = (const float*)d_in[14];
  float* out = (float*)d_out;

  char* ws = (char*)d_ws;
  int*   dmax = (int*)(ws + OFF_DMAX);
  float* degn = (float*)(ws + OFF_DEGN);
  short* blob = (short*)(ws + OFF_FRAG);
  float* A    = (float*)(ws + OFF_A);
  short* yfw  = (short*)(ws + OFF_YF);
  short* ybw  = (short*)(ws + OFF_YB);
  short* hfb  = (short*)(ws + OFF_HFB);

  k_zero<<<1, 64, 0, stream>>>(dmax);
  k_degmax<<<(SS*NN*LLEN + 255)/256, 256, 0, stream>>>(walks, indeg, dmax);
  k_degn<<<(NN + 255)/256, 256, 0, stream>>>(indeg, dmax, degn);
  k_prep<<<156, 64, 0, stream>>>(Wf, Uf, bif, bhf, Wb, Ub, bib, bhb, W, U, bh, blob);
  k_A<<<(NN + 31)/32, 192, 0, stream>>>(h, W, bi, A);
  k_fb<<<dim3(BB/64, 2), 128, 0, stream>>>(walks, blob, bhf, bhb, yfw, ybw, hfb);
  k_final<<<BB/64, 128, 0, stream>>>(walks, degn, A, blob, bh, yfw, ybw, hfb, out);
}

// Round 8
// 398.686 us; speedup vs baseline: 1.1993x; 1.1993x over previous
//
#include <hip/hip_runtime.h>
#include <hip/hip_bf16.h>

#define NN   10000
#define SS   4
#define BB   40000
#define LLEN 8
#define DD   193
#define G3   192
#define SPB  128          // seqs per block (8 waves x 16)
#define THREADS 512

typedef __attribute__((ext_vector_type(8))) short bf16x8;
typedef __attribute__((ext_vector_type(4))) short short4v;
typedef __attribute__((ext_vector_type(4))) float f32x4;

// ws layout (bytes)
#define OFF_DMAX 0
#define OFF_DEGN 1024
#define OFF_A    262144                // 10000*192*4 = 7.68 MB

__device__ __forceinline__ float sigm(float x){ return 1.0f/(1.0f+__expf(-x)); }
__device__ __forceinline__ float tanh_(float x){
  float e = __expf(-2.0f*fabsf(x));
  float t = (1.0f-e)/(1.0f+e);
  return x>=0.0f ? t : -t;
}
__device__ __forceinline__ short f2b(float f){            // RNE float->bf16
  unsigned u = __builtin_bit_cast(unsigned, f);
  u = u + 0x7FFFu + ((u>>16)&1u);
  return (short)(u>>16);
}
__device__ __forceinline__ float b2f(short s){
  unsigned u = ((unsigned)(unsigned short)s)<<16;
  return __builtin_bit_cast(float, u);
}

__global__ void k_zero(int* dmax){
  if (threadIdx.x==0 && blockIdx.x==0) *dmax = 0;
}

__global__ void k_degmax(const int* __restrict__ walks, const int* __restrict__ indeg,
                         int* __restrict__ dmax){
  int i = blockIdx.x*blockDim.x + threadIdx.x;
  int d = 0;
  if (i < SS*NN*LLEN) d = indeg[walks[i]];
  #pragma unroll
  for (int off=32; off>0; off>>=1) d = max(d, __shfl_xor(d, off));
  if ((threadIdx.x&63)==0 && d>0) atomicMax(dmax, d);
}

__global__ void k_degn(const int* __restrict__ indeg, const int* __restrict__ dmax,
                       float* __restrict__ degn){
  int n = blockIdx.x*blockDim.x + threadIdx.x;
  if (n < NN) degn[n] = (float)indeg[n] / (float)(*dmax);
}

// A[n][g] = bih[g] + sum_k h[n][k]*Wih[g][k]  (cols 0..63)  -- fp32, validated R5
__global__ __launch_bounds__(192) void k_A(const float* __restrict__ h,
                                           const float* __restrict__ Wih,
                                           const float* __restrict__ bih,
                                           float* __restrict__ A){
  int g = threadIdx.x;
  float w[64];
  #pragma unroll
  for (int k=0;k<64;++k) w[k] = Wih[g*DD + k];
  float bg = bih[g];
  __shared__ float hs[64];
  int n0 = blockIdx.x*32;
  for (int j=0;j<32;++j){
    int n = n0 + j;
    if (n >= NN) break;
    __syncthreads();
    if (g < 64) hs[g] = h[n*64+g];
    __syncthreads();
    float acc = bg;
    #pragma unroll
    for (int k=0;k<64;++k) acc += w[k]*hs[k];
    A[n*G3 + g] = acc;
  }
}

// ---------------- fused fwd+bwd+final GRU ----------------
// 8 waves x 16 seqs. Phase-staged weights in fragment-linear LDS (contiguous
// ds_read_b128 per frag). y[t] kept in VGPRs: the B-frag readback of h after
// each step IS y[t]. No y/hfb HBM traffic.
__global__ __launch_bounds__(THREADS, 2) void k_fused(
    const int* __restrict__ walks, const float* __restrict__ degn,
    const float* __restrict__ A,
    const float* __restrict__ Whh_f, const float* __restrict__ Wih_f,
    const float* __restrict__ bih_f, const float* __restrict__ bhh_f,
    const float* __restrict__ Whh_b, const float* __restrict__ Wih_b,
    const float* __restrict__ bih_b, const float* __restrict__ bhh_b,
    const float* __restrict__ W, const float* __restrict__ U,
    const float* __restrict__ bhh,
    float* __restrict__ out)
{
  __shared__ __align__(16) short WL[84*512];     // 84 frags x 1KB (phase-overlaid)
  __shared__ __align__(16) short hl[SPB*64];     // h state, XOR-swizzled
  __shared__ __align__(16) float sc[SPB*8*2];
  __shared__ __align__(16) int   node[SPB*8];
  __shared__ __align__(16) float degl[SPB*8];
  __shared__ __align__(16) float bhn[64];

  const int tid = threadIdx.x;
  const int b0  = blockIdx.x*SPB;

  // ---- prologue: per-(s,t) sin/cos, node, deg ----
  for (int idx = tid; idx < SPB*8; idx += THREADS){
    int s = idx>>3, t = idx&7, p = 7-t;
    long bsg = b0 + s; if (bsg >= BB) bsg = BB-1;
    const int* wr = walks + bsg*LLEN;
    int wp = wr[p]; int u = 7;
    #pragma unroll
    for (int j=7;j>=0;--j) if (wr[j]==wp) u = j;
    float si, ci;
    __sincosf((float)u * 0.7853981633974483f, &si, &ci);
    sc[idx*2] = si; sc[idx*2+1] = ci;
    node[idx] = wp;
    degl[idx] = degn[wp];
  }

  // ---- staging helpers ----
  auto stage_fb = [&](const float* Whh, const float* Wih,
                      const float* bih, const float* bhd){
    for (int sl = tid; sl < 36*64; sl += THREADS){
      int f = sl>>6, ln = sl&63;
      int ch = f%3, gt = (f/3)%3, q = f/9;
      int g = gt*64 + q*16 + (ln&15);
      int kb = (ln>>4)*8;
      short v[8];
      if (ch < 2){
        #pragma unroll
        for (int j=0;j<8;++j) v[j] = f2b(Whh[g*64 + ch*32 + kb + j]);
      } else {
        #pragma unroll
        for (int j=0;j<8;++j){
          int kk = kb + j;
          v[j] = (kk==0) ? f2b(Wih[2*g]) : (kk==1) ? f2b(Wih[2*g+1])
               : (kk==2) ? f2b(bih[g] + (g<128 ? bhd[g] : 0.0f)) : (short)0;
        }
      }
      *(bf16x8*)&WL[sl*8] = *(bf16x8*)v;
    }
    if (tid < 64) bhn[tid] = bhd[128+tid];
  };
  auto stage_final = [&](){
    for (int sl = tid; sl < 84*64; sl += THREADS){
      int f = sl>>6, ln = sl&63;
      int ch = f%7, gt = (f/7)%3, q = f/21;
      int g = gt*64 + q*16 + (ln&15);
      int kb = (ln>>4)*8;
      short v[8];
      if (ch < 2){
        #pragma unroll
        for (int j=0;j<8;++j) v[j] = f2b(U[g*64 + ch*32 + kb + j]);
      } else if (ch < 6){
        #pragma unroll
        for (int j=0;j<8;++j) v[j] = f2b(W[(long)g*DD + 64 + (ch-2)*32 + kb + j]);
      } else {
        #pragma unroll
        for (int j=0;j<8;++j){
          int kk = kb + j;
          v[j] = (kk==0) ? f2b(W[(long)g*DD + 192])
               : (kk==1) ? f2b(g<128 ? bhh[g] : 0.0f) : (short)0;
        }
      }
      *(bf16x8*)&WL[sl*8] = *(bf16x8*)v;
    }
    if (tid < 64) bhn[tid] = bhh[128+tid];
  };

  stage_fb(Whh_f, Wih_f, bih_f, bhh_f);
  __syncthreads();

  const int lane = tid & 63;
  const int wv   = tid >> 6;
  const int c    = lane & 15;
  const int a    = lane >> 4;
  const int s    = wv*16 + c;        // block-local seq row 0..127
  const long sg  = b0 + s;
  const int swz  = (s&7)<<3;

  const bf16x8 zf = {0,0,0,0,0,0,0,0};
  float hreg[4][4];
  bf16x8 bh0 = zf, bh1 = zf;
  bf16x8 yfr0[8], yfr1[8], ybr0[8], ybr1[8];

  #pragma unroll
  for (int q=0;q<4;++q)
    #pragma unroll
    for (int r=0;r<4;++r) hreg[q][r] = 0.0f;

  // fwd/bwd step body
#define GRU_FB_STEP(t)                                                          \
  {                                                                             \
    bf16x8 b2 = zf;                                                             \
    if (a == 0){                                                                \
      b2[0] = f2b(sc[(s*8+(t))*2]); b2[1] = f2b(sc[(s*8+(t))*2+1]);             \
      b2[2] = (short)0x3F80;                                                    \
    }                                                                           \
    _Pragma("unroll")                                                           \
    for (int q=0;q<4;++q){                                                      \
      f32x4 ar = {0,0,0,0}, az = {0,0,0,0}, an1 = {0,0,0,0}, an2 = {0,0,0,0};   \
      _Pragma("unroll")                                                         \
      for (int ch=0; ch<3; ++ch){                                               \
        bf16x8 fr = *(const bf16x8*)&WL[(((q*3+0)*3+ch)<<9) + lane*8];          \
        bf16x8 fz = *(const bf16x8*)&WL[(((q*3+1)*3+ch)<<9) + lane*8];          \
        bf16x8 fn = *(const bf16x8*)&WL[(((q*3+2)*3+ch)<<9) + lane*8];          \
        bf16x8 bb = (ch==0) ? bh0 : (ch==1) ? bh1 : b2;                         \
        ar = __builtin_amdgcn_mfma_f32_16x16x32_bf16(fr, bb, ar, 0,0,0);        \
        az = __builtin_amdgcn_mfma_f32_16x16x32_bf16(fz, bb, az, 0,0,0);        \
        if (ch < 2) an1 = __builtin_amdgcn_mfma_f32_16x16x32_bf16(fn, bb, an1, 0,0,0); \
        else        an2 = __builtin_amdgcn_mfma_f32_16x16x32_bf16(fn, bb, an2, 0,0,0); \
      }                                                                         \
      f32x4 bv = *(const f32x4*)&bhn[q*16 + 4*a];                               \
      short4v pack;                                                             \
      _Pragma("unroll")                                                         \
      for (int r=0;r<4;++r){                                                    \
        float rr = sigm(ar[r]);                                                 \
        float zz = sigm(az[r]);                                                 \
        float nn = tanh_(an2[r] + rr*(an1[r] + bv[r]));                         \
        float hv = (1.0f-zz)*nn + zz*hreg[q][r];                                \
        hreg[q][r] = hv;                                                        \
        pack[r] = f2b(hv);                                                      \
      }                                                                         \
      *(short4v*)&hl[s*64 + ((q*16 + 4*a) ^ swz)] = pack;                       \
    }                                                                           \
    bh0 = *(const bf16x8*)&hl[s*64 + ((a*8)      ^ swz)];                       \
    bh1 = *(const bf16x8*)&hl[s*64 + ((32 + a*8) ^ swz)];                       \
  }

  // ---- FWD ----
  #pragma unroll
  for (int ss=0; ss<8; ++ss){
    GRU_FB_STEP(ss)
    yfr0[ss] = bh0; yfr1[ss] = bh1;
  }
  __syncthreads();
  stage_fb(Whh_b, Wih_b, bih_b, bhh_b);
  __syncthreads();

  // ---- BWD ----
  bh0 = zf; bh1 = zf;
  #pragma unroll
  for (int q=0;q<4;++q)
    #pragma unroll
    for (int r=0;r<4;++r) hreg[q][r] = 0.0f;
  #pragma unroll
  for (int ss=0; ss<8; ++ss){
    const int t = 7-ss;
    GRU_FB_STEP(t)
    ybr0[t] = bh0; ybr1[t] = bh1;
  }
  __syncthreads();
  stage_final();
  __syncthreads();

  // ---- h_walk = 0.5*(hf + hb): hf = yfr[7], hb = ybr[0] ----
  {
    bf16x8 hw0, hw1;
    #pragma unroll
    for (int j=0;j<8;++j){
      hw0[j] = f2b(0.5f*(b2f(yfr0[7][j]) + b2f(ybr0[0][j])));
      hw1[j] = f2b(0.5f*(b2f(yfr1[7][j]) + b2f(ybr1[0][j])));
    }
    *(bf16x8*)&hl[s*64 + ((a*8)      ^ swz)] = hw0;
    *(bf16x8*)&hl[s*64 + ((32 + a*8) ^ swz)] = hw1;
    bh0 = hw0; bh1 = hw1;
    #pragma unroll
    for (int q=0;q<4;++q){
      short4v h4 = *(const short4v*)&hl[s*64 + ((q*16 + 4*a) ^ swz)];
      #pragma unroll
      for (int r=0;r<4;++r) hreg[q][r] = b2f(h4[r]);
    }
  }

  // ---- FINAL ----
  #pragma unroll
  for (int t=0; t<8; ++t){
    bf16x8 b5 = zf;
    if (a == 0){ b5[0] = f2b(degl[s*8+t]); b5[1] = (short)0x3F80; }
    const int nd = node[s*8+t];
    const bf16x8 yy0 = yfr0[t], yy1 = yfr1[t], yy2 = ybr0[t], yy3 = ybr1[t];

    #pragma unroll
    for (int q=0;q<4;++q){
      f32x4 ar = {0,0,0,0}, az = {0,0,0,0}, an1 = {0,0,0,0}, an2 = {0,0,0,0};
      #pragma unroll
      for (int ch=0; ch<7; ++ch){
        bf16x8 fr = *(const bf16x8*)&WL[(((q*3+0)*7+ch)<<9) + lane*8];
        bf16x8 fz = *(const bf16x8*)&WL[(((q*3+1)*7+ch)<<9) + lane*8];
        bf16x8 fn = *(const bf16x8*)&WL[(((q*3+2)*7+ch)<<9) + lane*8];
        bf16x8 bb = (ch==0) ? bh0 : (ch==1) ? bh1
                  : (ch==2) ? yy0 : (ch==3) ? yy1
                  : (ch==4) ? yy2 : (ch==5) ? yy3 : b5;
        ar = __builtin_amdgcn_mfma_f32_16x16x32_bf16(fr, bb, ar, 0,0,0);
        az = __builtin_amdgcn_mfma_f32_16x16x32_bf16(fz, bb, az, 0,0,0);
        if (ch < 2) an1 = __builtin_amdgcn_mfma_f32_16x16x32_bf16(fn, bb, an1, 0,0,0);
        else        an2 = __builtin_amdgcn_mfma_f32_16x16x32_bf16(fn, bb, an2, 0,0,0);
      }
      const float* Ab = A + (long)nd*G3 + q*16 + 4*a;
      f32x4 Agr = *(const f32x4*)(Ab);
      f32x4 Agz = *(const f32x4*)(Ab + 64);
      f32x4 Agn = *(const f32x4*)(Ab + 128);
      f32x4 bv  = *(const f32x4*)&bhn[q*16 + 4*a];
      short4v pack;
      #pragma unroll
      for (int r=0;r<4;++r){
        float rr = sigm(ar[r] + Agr[r]);
        float zz = sigm(az[r] + Agz[r]);
        float nn = tanh_(an2[r] + Agn[r] + rr*(an1[r] + bv[r]));
        float hv = (1.0f-zz)*nn + zz*hreg[q][r];
        hreg[q][r] = hv;
        pack[r] = f2b(hv);
      }
      *(short4v*)&hl[s*64 + ((q*16 + 4*a) ^ swz)] = pack;
    }
    if (t < 7){
      bh0 = *(const bf16x8*)&hl[s*64 + ((a*8)      ^ swz)];
      bh1 = *(const bf16x8*)&hl[s*64 + ((32 + a*8) ^ swz)];
    }
  }

  // ---- out ----
  if (sg < BB){
    #pragma unroll
    for (int q=0;q<4;++q){
      f32x4 o;
      #pragma unroll
      for (int r=0;r<4;++r) o[r] = hreg[q][r];
      *(f32x4*)(out + sg*64 + q*16 + 4*a) = o;
    }
  }
#undef GRU_FB_STEP
}

extern "C" void kernel_launch(void* const* d_in, const int* in_sizes, int n_in,
                              void* d_out, int out_size, void* d_ws, size_t ws_size,
                              hipStream_t stream) {
  const float* h     = (const float*)d_in[0];
  const int*   walks = (const int*)d_in[1];
  const int*   indeg = (const int*)d_in[2];
  const float* Wf    = (const float*)d_in[3];
  const float* Uf    = (const float*)d_in[4];
  const float* bif   = (const float*)d_in[5];
  const float* bhf   = (const float*)d_in[6];
  const float* Wb    = (const float*)d_in[7];
  const float* Ub    = (const float*)d_in[8];
  const float* bib   = (const float*)d_in[9];
  const float* bhb   = (const float*)d_in[10];
  const float* W     = (const float*)d_in[11];
  const float* U     = (const float*)d_in[12];
  const float* bi    = (const float*)d_in[13];
  const float* bh    = (const float*)d_in[14];
  float* out = (float*)d_out;

  char* ws = (char*)d_ws;
  int*   dmax = (int*)(ws + OFF_DMAX);
  float* degn = (float*)(ws + OFF_DEGN);
  float* A    = (float*)(ws + OFF_A);

  k_zero<<<1, 64, 0, stream>>>(dmax);
  k_degmax<<<(SS*NN*LLEN + 255)/256, 256, 0, stream>>>(walks, indeg, dmax);
  k_degn<<<(NN + 255)/256, 256, 0, stream>>>(indeg, dmax, degn);
  k_A<<<(NN + 31)/32, 192, 0, stream>>>(h, W, bi, A);
  k_fused<<<(BB + SPB - 1)/SPB, THREADS, 0, stream>>>(
      walks, degn, A,
      Uf, Wf, bif, bhf,      // Whh_f, Wih_f, bih_f, bhh_f
      Ub, Wb, bib, bhb,      // Whh_b, Wih_b, bih_b, bhh_b
      W, U, bh, out);
}